// Round 3
// baseline (223.486 us; speedup 1.0000x reference)
//
#include <hip/hip_runtime.h>
#include <hip/hip_cooperative_groups.h>
#include <cmath>

namespace cg = cooperative_groups;

constexpr int B_ = 2, H_ = 8, N_ = 2048, DK_ = 64, DV_ = 64;
constexpr int BH_ = B_ * H_;      // 16
constexpr int C_ = 64;            // chunk size
constexpr int NC_ = N_ / C_;      // 32 chunks per (b,h)
constexpr int NCH_ = BH_ * NC_;   // 512 chunks total

// ===========================================================================
// Fused cooperative kernel, 512 blocks x 1024 threads (= 8192 waves = 100%
// wave occupancy at 2 blocks/CU; LDS 64.75KB*2=130KB<=160KB, VGPR capped 64).
// ===========================================================================
__global__ __launch_bounds__(1024, 8) void fused2(
    const float* __restrict__ qg, const float* __restrict__ kg,
    const float* __restrict__ vg, const float* __restrict__ om,
    float* __restrict__ lksum, float* __restrict__ lkv,
    float* __restrict__ pksum, float* __restrict__ pkv,
    float* __restrict__ outg)
{
  __shared__ float kb[C_][DK_];     // kbar row-major; phase3 reused as odm
  __shared__ float kbT[DK_][C_];    // kbar^T; phase3 reused as St
  __shared__ float vs[C_][DV_];
  __shared__ float qbT[DK_][C_];
  __shared__ float smqc[C_], smkc[C_], ppm[C_];

  const int chunk = blockIdx.x;
  const int bh = chunk >> 5, ci = chunk & 31;
  const int r0 = ci * C_;
  const size_t gbase = (size_t)(bh * N_ + r0) * DK_;
  const int t = threadIdx.x;

  // Early q/k/v loads (1 float4 each; 4096 floats per chunk / 1024 threads).
  const float4 k4g = *(const float4*)(kg + gbase + (size_t)t * 4);
  const float4 v4g = *(const float4*)(vg + gbase + (size_t)t * 4);
  const float4 q4g = *(const float4*)(qg + gbase + (size_t)t * 4);

  // ---- Phase 0: omask row sums; 16 waves x 4 rows each ----
  {
    const int w = t >> 6, lane = t & 63;
    const float* ob = om + (size_t)(bh * N_ + r0) * N_;
    for (int rr = 0; rr < 4; ++rr) {
      const int row = w * 4 + rr;
      const float* rp = ob + (size_t)row * N_;
      float s = 0.f;
#pragma unroll
      for (int kk = 0; kk < 8; ++kk) {
        float4 x = *(const float4*)(rp + kk * 256 + lane * 4);
        s += (x.x + x.y) + (x.z + x.w);
      }
#pragma unroll
      for (int off = 32; off; off >>= 1) s += __shfl_xor(s, off, 64);
      if (lane == 0) {
        float o0 = rp[0];
        smqc[row] = o0 / sqrtf(s);
        smkc[row] = 1.0f / o0;
      }
    }
  }
  __syncthreads();

  // ---- Stage kbar (row + transposed), v, qbar^T ----
  {
    int row = t >> 4, col = (t & 15) * 4;
    float kcv = smkc[row], qcv = smqc[row];
    float4 k4 = k4g;
    k4.x *= kcv; k4.y *= kcv; k4.z *= kcv; k4.w *= kcv;
    *(float4*)&kb[row][col] = k4;
    kbT[col + 0][row] = k4.x; kbT[col + 1][row] = k4.y;
    kbT[col + 2][row] = k4.z; kbT[col + 3][row] = k4.w;
    *(float4*)&vs[row][col] = v4g;
    qbT[col + 0][row] = q4g.x * qcv; qbT[col + 1][row] = q4g.y * qcv;
    qbT[col + 2][row] = q4g.z * qcv; qbT[col + 3][row] = q4g.w * qcv;
  }
  __syncthreads();

  // ---- Phase 1: chunk-local sums (4x4 per thread, 256 active threads) ----
  if (t < 256) {
    int dk0 = (t & 15) * 4, dv0 = (t >> 4) * 4;
    float acc[4][4] = {};
    float ks[4] = {};
    for (int r = 0; r < C_; ++r) {
      float4 k4 = *(const float4*)&kb[r][dk0];
      float4 v4 = *(const float4*)&vs[r][dv0];
      float ka[4] = {k4.x, k4.y, k4.z, k4.w};
      float va[4] = {v4.x, v4.y, v4.z, v4.w};
#pragma unroll
      for (int i = 0; i < 4; ++i) {
        ks[i] += ka[i];
#pragma unroll
        for (int j = 0; j < 4; ++j) acc[i][j] += ka[i] * va[j];
      }
    }
    float* kvc = lkv + (size_t)chunk * (DK_ * DV_);
#pragma unroll
    for (int i = 0; i < 4; ++i)
      *(float4*)(kvc + (size_t)(dk0 + i) * DV_ + dv0) =
          make_float4(acc[i][0], acc[i][1], acc[i][2], acc[i][3]);
    if (t < 16) {
#pragma unroll
      for (int i = 0; i < 4; ++i) lksum[(size_t)chunk * DK_ + dk0 + i] = ks[i];
    }
  }

  cg::this_grid().sync();

  // ---- Phase 2: exclusive prefix scan, 130 elements per block ----
  {
    constexpr int PER = DK_ * DV_ + DK_;          // 4160 per bh
    int g = blockIdx.x * 130 + t;                 // 512*130 = 66560 = 16*PER
    if (t < 130) {
      int sbh = g / PER, e = g - sbh * PER;
      float run = 0.f;
      if (e < DK_ * DV_) {
        const float* src = lkv + (size_t)sbh * NC_ * (DK_ * DV_) + e;
        float* dst = pkv + (size_t)sbh * NC_ * (DK_ * DV_) + e;
        for (int cc = 0; cc < NC_; ++cc) {
          dst[(size_t)cc * (DK_ * DV_)] = run;
          run += src[(size_t)cc * (DK_ * DV_)];
        }
      } else {
        int e2 = e - DK_ * DV_;
        const float* src = lksum + (size_t)sbh * NC_ * DK_ + e2;
        float* dst = pksum + (size_t)sbh * NC_ * DK_ + e2;
        for (int cc = 0; cc < NC_; ++cc) {
          dst[(size_t)cc * DK_] = run;
          run += src[(size_t)cc * DK_];
        }
      }
    }
  }

  cg::this_grid().sync();

  // ---- Phase 3: S tile (waves 0-3) || qb*Dpre part (waves 4-7) ----
  float (*odm)[DK_] = kb;          // reuse kb as the D-part output
  float accS[4][4] = {};
  if (t < 256) {
    int i0 = (t & 15) * 4, j0 = (t >> 4) * 4;
    for (int a = 0; a < DK_; ++a) {
      float4 q4 = *(const float4*)&qbT[a][i0];
      float4 k4 = *(const float4*)&kbT[a][j0];
      float qa[4] = {q4.x, q4.y, q4.z, q4.w};
      float kk[4] = {k4.x, k4.y, k4.z, k4.w};
#pragma unroll
      for (int ii = 0; ii < 4; ++ii)
#pragma unroll
        for (int jj = 0; jj < 4; ++jj) accS[ii][jj] += qa[ii] * kk[jj];
    }
  } else if (t < 512) {
    int u = t - 256;
    int bi0 = (u >> 4) * 4, c0 = (u & 15) * 4;
    const float* kvp = pkv + (size_t)chunk * (DK_ * DV_);
    const float* tp = pksum + (size_t)chunk * DK_;
    float o1[4][4] = {};
    float pp1[4] = {};
    for (int a = 0; a < DK_; ++a) {
      float4 q4 = *(const float4*)&qbT[a][bi0];
      float4 d4 = *(const float4*)(kvp + (size_t)a * DV_ + c0);
      float tv = tp[a];
      float qa[4] = {q4.x, q4.y, q4.z, q4.w};
      float da[4] = {d4.x, d4.y, d4.z, d4.w};
#pragma unroll
      for (int ii = 0; ii < 4; ++ii) {
        pp1[ii] += qa[ii] * tv;
#pragma unroll
        for (int cc = 0; cc < 4; ++cc) o1[ii][cc] += qa[ii] * da[cc];
      }
    }
#pragma unroll
    for (int ii = 0; ii < 4; ++ii)
      *(float4*)&odm[bi0 + ii][c0] =
          make_float4(o1[ii][0], o1[ii][1], o1[ii][2], o1[ii][3]);
    if ((u & 15) == 0) {
#pragma unroll
      for (int ii = 0; ii < 4; ++ii) ppm[bi0 + ii] = pp1[ii];
    }
  }
  __syncthreads();                 // A done reading kbT; odm/ppm written
  if (t < 256) {                   // causal-masked transposed S into kbT
    int i0 = (t & 15) * 4, j0 = (t >> 4) * 4;
    float (*St)[C_] = kbT;
#pragma unroll
    for (int jj = 0; jj < 4; ++jj) {
      int j = j0 + jj;
      float4 w;
      w.x = (j <= i0 + 0) ? accS[0][jj] : 0.f;
      w.y = (j <= i0 + 1) ? accS[1][jj] : 0.f;
      w.z = (j <= i0 + 2) ? accS[2][jj] : 0.f;
      w.w = (j <= i0 + 3) ? accS[3][jj] : 0.f;
      *(float4*)&St[j][i0] = w;
    }
  }
  __syncthreads();
  if (t < 256) {                   // O = S*V + odm ; P = ppm + rowsum(S)
    int bi0 = (t >> 4) * 4, c0 = (t & 15) * 4;
    float (*St)[C_] = kbT;
    float o[4][4] = {};
    float ppS[4] = {};
    for (int j = 0; j < C_; ++j) {
      float4 s4 = *(const float4*)&St[j][bi0];
      float4 v4 = *(const float4*)&vs[j][c0];
      float sa[4] = {s4.x, s4.y, s4.z, s4.w};
      float va[4] = {v4.x, v4.y, v4.z, v4.w};
#pragma unroll
      for (int ii = 0; ii < 4; ++ii) {
        ppS[ii] += sa[ii];
#pragma unroll
        for (int cc = 0; cc < 4; ++cc) o[ii][cc] += sa[ii] * va[cc];
      }
    }
    float* obp = outg + (size_t)(bh * N_ + r0) * DV_;
#pragma unroll
    for (int ii = 0; ii < 4; ++ii) {
      int row = bi0 + ii;
      float P = fmaxf(fabsf(ppm[row] + ppS[ii]), 1.0f);
      float inv = 1.0f / P;
      float4 w = make_float4((o[ii][0] + odm[row][c0 + 0]) * inv,
                             (o[ii][1] + odm[row][c0 + 1]) * inv,
                             (o[ii][2] + odm[row][c0 + 2]) * inv,
                             (o[ii][3] + odm[row][c0 + 3]) * inv);
      *(float4*)(obp + (size_t)row * DV_ + c0) = w;
    }
  }
}

// ===========================================================================
// Fallback path (round-1 proven 4-kernel split) in case the cooperative
// launch is rejected by the occupancy check on some runtime.
// ===========================================================================
__global__ __launch_bounds__(256) void coef_kernel(const float* __restrict__ om,
                                                   float* __restrict__ qc,
                                                   float* __restrict__ kc) {
  int row = blockIdx.x * 4 + (threadIdx.x >> 6);
  int lane = threadIdx.x & 63;
  const float* r = om + (size_t)row * N_;
  float s = 0.f;
#pragma unroll
  for (int kk = 0; kk < N_ / 256; ++kk) {
    float4 v4 = *(const float4*)(r + kk * 256 + lane * 4);
    s += (v4.x + v4.y) + (v4.z + v4.w);
  }
#pragma unroll
  for (int off = 32; off > 0; off >>= 1) s += __shfl_xor(s, off, 64);
  if (lane == 0) {
    float o0 = r[0];
    qc[row] = o0 / sqrtf(s);
    kc[row] = 1.0f / o0;
  }
}

__global__ __launch_bounds__(256) void chunksum_kernel(const float* __restrict__ kg,
                                                       const float* __restrict__ vg,
                                                       const float* __restrict__ kc,
                                                       float* __restrict__ ksum,
                                                       float* __restrict__ kvsum) {
  __shared__ float kb[C_][DK_];
  __shared__ float vs[C_][DV_];
  int chunk = blockIdx.x;
  int bh = chunk / NC_, ci = chunk - bh * NC_;
  int r0 = ci * C_;
  size_t gbase = ((size_t)bh * N_ + r0) * DK_;
  int t = threadIdx.x;
#pragma unroll
  for (int p = 0; p < 4; ++p) {
    int f = t + p * 256;
    int row = f >> 4, col = (f & 15) * 4;
    float sc = kc[bh * N_ + r0 + row];
    float4 k4 = *(const float4*)(kg + gbase + (size_t)f * 4);
    k4.x *= sc; k4.y *= sc; k4.z *= sc; k4.w *= sc;
    *(float4*)&kb[row][col] = k4;
    *(float4*)&vs[row][col] = *(const float4*)(vg + gbase + (size_t)f * 4);
  }
  __syncthreads();
  int dk0 = (t & 15) * 4, dv0 = (t >> 4) * 4;
  float acc[4][4] = {};
  float ks[4] = {};
  for (int r = 0; r < C_; ++r) {
    float4 k4 = *(const float4*)&kb[r][dk0];
    float4 v4 = *(const float4*)&vs[r][dv0];
    float ka[4] = {k4.x, k4.y, k4.z, k4.w};
    float va[4] = {v4.x, v4.y, v4.z, v4.w};
#pragma unroll
    for (int i = 0; i < 4; ++i) {
      ks[i] += ka[i];
#pragma unroll
      for (int j = 0; j < 4; ++j) acc[i][j] += ka[i] * va[j];
    }
  }
  float* kvc = kvsum + (size_t)chunk * (DK_ * DV_);
#pragma unroll
  for (int i = 0; i < 4; ++i)
    *(float4*)(kvc + (size_t)(dk0 + i) * DV_ + dv0) =
        make_float4(acc[i][0], acc[i][1], acc[i][2], acc[i][3]);
  if (t < 16) {
#pragma unroll
    for (int i = 0; i < 4; ++i) ksum[(size_t)chunk * DK_ + dk0 + i] = ks[i];
  }
}

__global__ __launch_bounds__(256) void scan_kernel(const float* __restrict__ lks,
                                                   const float* __restrict__ lkv,
                                                   float* __restrict__ pks,
                                                   float* __restrict__ pkv) {
  constexpr int PER = DK_ * DV_ + DK_;
  int idx = blockIdx.x * 256 + threadIdx.x;
  if (idx >= BH_ * PER) return;
  int bh = idx / PER, e = idx - bh * PER;
  float run = 0.f;
  if (e < DK_ * DV_) {
    const float* src = lkv + (size_t)bh * NC_ * (DK_ * DV_) + e;
    float* dst = pkv + (size_t)bh * NC_ * (DK_ * DV_) + e;
    for (int ci = 0; ci < NC_; ++ci) {
      dst[(size_t)ci * (DK_ * DV_)] = run;
      run += src[(size_t)ci * (DK_ * DV_)];
    }
  } else {
    const float* src = lks + (size_t)bh * NC_ * DK_ + (e - DK_ * DV_);
    float* dst = pks + (size_t)bh * NC_ * DK_ + (e - DK_ * DV_);
    for (int ci = 0; ci < NC_; ++ci) {
      dst[(size_t)ci * DK_] = run;
      run += src[(size_t)ci * DK_];
    }
  }
}

__global__ __launch_bounds__(256) void out_kernel(const float* __restrict__ qg,
                                                  const float* __restrict__ kg,
                                                  const float* __restrict__ vg,
                                                  const float* __restrict__ qc,
                                                  const float* __restrict__ kc,
                                                  const float* __restrict__ ksum,
                                                  const float* __restrict__ kvsum,
                                                  float* __restrict__ outg) {
  __shared__ float qbT[DK_][C_];
  __shared__ float kbT[DK_][C_];
  __shared__ float vs[C_][DV_];
  int chunk = blockIdx.x;
  int bh = chunk / NC_, ci = chunk - bh * NC_;
  int r0 = ci * C_;
  size_t gbase = ((size_t)bh * N_ + r0) * DK_;
  int t = threadIdx.x;
  {
    int i = t & 63;
    int apart = t >> 6;
    float qsc = qc[bh * N_ + r0 + i];
    float ksc = kc[bh * N_ + r0 + i];
#pragma unroll
    for (int u = 0; u < 4; ++u) {
      int a0 = apart * 16 + u * 4;
      float4 q4 = *(const float4*)(qg + gbase + (size_t)i * DK_ + a0);
      float4 k4 = *(const float4*)(kg + gbase + (size_t)i * DK_ + a0);
      qbT[a0 + 0][i] = q4.x * qsc; qbT[a0 + 1][i] = q4.y * qsc;
      qbT[a0 + 2][i] = q4.z * qsc; qbT[a0 + 3][i] = q4.w * qsc;
      kbT[a0 + 0][i] = k4.x * ksc; kbT[a0 + 1][i] = k4.y * ksc;
      kbT[a0 + 2][i] = k4.z * ksc; kbT[a0 + 3][i] = k4.w * ksc;
    }
#pragma unroll
    for (int p = 0; p < 4; ++p) {
      int f = t + p * 256;
      int row = f >> 4, col = (f & 15) * 4;
      *(float4*)&vs[row][col] = *(const float4*)(vg + gbase + (size_t)f * 4);
    }
  }
  __syncthreads();
  int i0 = (t & 15) * 4, j0 = (t >> 4) * 4;
  float acc[4][4] = {};
  for (int a = 0; a < DK_; ++a) {
    float4 q4 = *(const float4*)&qbT[a][i0];
    float4 k4 = *(const float4*)&kbT[a][j0];
    float qa[4] = {q4.x, q4.y, q4.z, q4.w};
    float kk[4] = {k4.x, k4.y, k4.z, k4.w};
#pragma unroll
    for (int ii = 0; ii < 4; ++ii)
#pragma unroll
      for (int jj = 0; jj < 4; ++jj) acc[ii][jj] += qa[ii] * kk[jj];
  }
  __syncthreads();
  float (*St)[C_] = kbT;
#pragma unroll
  for (int jj = 0; jj < 4; ++jj) {
    int j = j0 + jj;
    float4 w;
    w.x = (j <= i0 + 0) ? acc[0][jj] : 0.f;
    w.y = (j <= i0 + 1) ? acc[1][jj] : 0.f;
    w.z = (j <= i0 + 2) ? acc[2][jj] : 0.f;
    w.w = (j <= i0 + 3) ? acc[3][jj] : 0.f;
    *(float4*)&St[j][i0] = w;
  }
  __syncthreads();
  {
    int bi0 = (t >> 4) * 4, c0 = (t & 15) * 4;
    const float* kvp = kvsum + (size_t)chunk * (DK_ * DV_);
    const float* tp = ksum + (size_t)chunk * DK_;
    float o[4][4] = {};
    float pp[4] = {};
    for (int a = 0; a < DK_; ++a) {
      float4 q4 = *(const float4*)&qbT[a][bi0];
      float4 d4 = *(const float4*)(kvp + (size_t)a * DV_ + c0);
      float tv = tp[a];
      float qa[4] = {q4.x, q4.y, q4.z, q4.w};
      float da[4] = {d4.x, d4.y, d4.z, d4.w};
#pragma unroll
      for (int ii = 0; ii < 4; ++ii) {
        pp[ii] += qa[ii] * tv;
#pragma unroll
        for (int cc = 0; cc < 4; ++cc) o[ii][cc] += qa[ii] * da[cc];
      }
    }
    for (int j = 0; j < C_; ++j) {
      float4 s4 = *(const float4*)&St[j][bi0];
      float4 v4 = *(const float4*)&vs[j][c0];
      float sa[4] = {s4.x, s4.y, s4.z, s4.w};
      float va[4] = {v4.x, v4.y, v4.z, v4.w};
#pragma unroll
      for (int ii = 0; ii < 4; ++ii) {
        pp[ii] += sa[ii];
#pragma unroll
        for (int cc = 0; cc < 4; ++cc) o[ii][cc] += sa[ii] * va[cc];
      }
    }
    float* obp = outg + ((size_t)bh * N_ + r0) * DV_;
#pragma unroll
    for (int ii = 0; ii < 4; ++ii) {
      float P = fmaxf(fabsf(pp[ii]), 1.0f);
      float inv = 1.0f / P;
      *(float4*)(obp + (size_t)(bi0 + ii) * DV_ + c0) =
          make_float4(o[ii][0] * inv, o[ii][1] * inv,
                      o[ii][2] * inv, o[ii][3] * inv);
    }
  }
}

// ---------------------------------------------------------------------------
extern "C" void kernel_launch(void* const* d_in, const int* in_sizes, int n_in,
                              void* d_out, int out_size, void* d_ws, size_t ws_size,
                              hipStream_t stream) {
  const float* q = (const float*)d_in[0];
  const float* k = (const float*)d_in[1];
  const float* v = (const float*)d_in[2];
  const float* om = (const float*)d_in[3];
  float* out = (float*)d_out;

  float* ws = (float*)d_ws;
  float* lksum = ws;                               // NCH_*DK_
  float* lkv = lksum + (size_t)NCH_ * DK_;         // NCH_*DK_*DV_
  float* pksum = lkv + (size_t)NCH_ * DK_ * DV_;   // NCH_*DK_
  float* pkv = pksum + (size_t)NCH_ * DK_;         // NCH_*DK_*DV_

  void* args[] = {(void*)&q, (void*)&k, (void*)&v, (void*)&om,
                  (void*)&lksum, (void*)&lkv, (void*)&pksum, (void*)&pkv,
                  (void*)&out};
  hipError_t err = hipLaunchCooperativeKernel((void*)fused2, dim3(NCH_),
                                              dim3(1024), args, 0, stream);
  if (err != hipSuccess) {
    // Deterministic fallback: proven 4-kernel split (round-1 path).
    float* qc = pkv + (size_t)NCH_ * DK_ * DV_;    // reuse tail of ws
    float* kc = qc + BH_ * N_;
    coef_kernel<<<BH_ * N_ / 4, 256, 0, stream>>>(om, qc, kc);
    chunksum_kernel<<<NCH_, 256, 0, stream>>>(k, v, kc, lksum, lkv);
    constexpr int SCAN_TOTAL = BH_ * (DK_ * DV_ + DK_);
    scan_kernel<<<(SCAN_TOTAL + 255) / 256, 256, 0, stream>>>(lksum, lkv,
                                                              pksum, pkv);
    out_kernel<<<NCH_, 256, 0, stream>>>(q, k, v, qc, kc, pksum, pkv, out);
  }
}

// Round 4
// 82.056 us; speedup vs baseline: 2.7236x; 2.7236x over previous
//
#include <hip/hip_runtime.h>
#include <cmath>

constexpr int B_ = 2, H_ = 8, N_ = 2048, DK_ = 64, DV_ = 64;
constexpr int BH_ = B_ * H_;      // 16
constexpr int C_ = 64;            // chunk size
constexpr int NC_ = N_ / C_;      // 32 chunks per (b,h)
constexpr int NCH_ = BH_ * NC_;   // 512 chunks total

// ---------------------------------------------------------------------------
// Kernel 1: per-row coefficients. 2 rows per wave, loads interleaved so 16
// independent float4 loads are in flight before any reduce (round-1 had 8).
// qc[i] = omask[i,0]/sqrt(sum_j omask[i,j]);  kc[i] = 1/omask[i,0]
// ---------------------------------------------------------------------------
__global__ __launch_bounds__(256) void coef_kernel(const float* __restrict__ om,
                                                   float* __restrict__ qc,
                                                   float* __restrict__ kc) {
  int w = threadIdx.x >> 6, lane = threadIdx.x & 63;
  int row0 = blockIdx.x * 8 + w * 2;               // 2 rows per wave
  const float* r0p = om + (size_t)row0 * N_;
  const float* r1p = r0p + N_;
  float s0 = 0.f, s1 = 0.f;
#pragma unroll
  for (int kk = 0; kk < 8; ++kk) {
    float4 a = *(const float4*)(r0p + kk * 256 + lane * 4);
    float4 b = *(const float4*)(r1p + kk * 256 + lane * 4);
    s0 += (a.x + a.y) + (a.z + a.w);
    s1 += (b.x + b.y) + (b.z + b.w);
  }
#pragma unroll
  for (int off = 32; off; off >>= 1) {
    s0 += __shfl_xor(s0, off, 64);
    s1 += __shfl_xor(s1, off, 64);
  }
  if (lane == 0) {
    float o0 = r0p[0];
    qc[row0] = o0 / sqrtf(s0);
    kc[row0] = 1.0f / o0;
  } else if (lane == 1) {
    float o1 = r1p[0];
    qc[row0 + 1] = o1 / sqrtf(s1);
    kc[row0 + 1] = 1.0f / o1;
  }
}

// ---------------------------------------------------------------------------
// Kernel 2: per-chunk sums  ksum[dk] = sum_r kbar[r][dk],
//                           kv[dk][dv] = sum_r kbar[r][dk]*v[r][dv]
// ---------------------------------------------------------------------------
__global__ __launch_bounds__(256) void chunksum_kernel(const float* __restrict__ kg,
                                                       const float* __restrict__ vg,
                                                       const float* __restrict__ kc,
                                                       float* __restrict__ ksum,
                                                       float* __restrict__ kvsum) {
  __shared__ float kb[C_][DK_];
  __shared__ float vs[C_][DV_];
  int chunk = blockIdx.x;
  int bh = chunk / NC_, ci = chunk - bh * NC_;
  int r0 = ci * C_;
  size_t gbase = ((size_t)bh * N_ + r0) * DK_;
  int t = threadIdx.x;
#pragma unroll
  for (int p = 0; p < 4; ++p) {
    int f = t + p * 256;
    int row = f >> 4, col = (f & 15) * 4;
    float sc = kc[bh * N_ + r0 + row];
    float4 k4 = *(const float4*)(kg + gbase + (size_t)f * 4);
    k4.x *= sc; k4.y *= sc; k4.z *= sc; k4.w *= sc;
    *(float4*)&kb[row][col] = k4;
    *(float4*)&vs[row][col] = *(const float4*)(vg + gbase + (size_t)f * 4);
  }
  __syncthreads();
  int dk0 = (t & 15) * 4, dv0 = (t >> 4) * 4;
  float acc[4][4] = {};
  float ks[4] = {};
  for (int r = 0; r < C_; ++r) {
    float4 k4 = *(const float4*)&kb[r][dk0];
    float4 v4 = *(const float4*)&vs[r][dv0];
    float ka[4] = {k4.x, k4.y, k4.z, k4.w};
    float va[4] = {v4.x, v4.y, v4.z, v4.w};
#pragma unroll
    for (int i = 0; i < 4; ++i) {
      ks[i] += ka[i];
#pragma unroll
      for (int j = 0; j < 4; ++j) acc[i][j] += ka[i] * va[j];
    }
  }
  float* kvc = kvsum + (size_t)chunk * (DK_ * DV_);
#pragma unroll
  for (int i = 0; i < 4; ++i)
    *(float4*)(kvc + (size_t)(dk0 + i) * DV_ + dv0) =
        make_float4(acc[i][0], acc[i][1], acc[i][2], acc[i][3]);
  if (t < 16) {
#pragma unroll
    for (int i = 0; i < 4; ++i) ksum[(size_t)chunk * DK_ + dk0 + i] = ks[i];
  }
}

// ---------------------------------------------------------------------------
// Kernel 3: exclusive prefix over chunks (per bh), float4 per thread.
// ---------------------------------------------------------------------------
__global__ __launch_bounds__(256) void scan_kernel(const float* __restrict__ lks,
                                                   const float* __restrict__ lkv,
                                                   float* __restrict__ pks,
                                                   float* __restrict__ pkv) {
  constexpr int PER4 = (DK_ * DV_) / 4 + DK_ / 4;   // 1024 + 16 = 1040
  int idx = blockIdx.x * 256 + threadIdx.x;
  if (idx >= BH_ * PER4) return;
  int bh = idx / PER4, e = idx - bh * PER4;
  float4 run = make_float4(0.f, 0.f, 0.f, 0.f);
  if (e < (DK_ * DV_) / 4) {
    const float4* src = (const float4*)(lkv + (size_t)bh * NC_ * (DK_ * DV_)) + e;
    float4* dst = (float4*)(pkv + (size_t)bh * NC_ * (DK_ * DV_)) + e;
    for (int cc = 0; cc < NC_; ++cc) {
      dst[(size_t)cc * ((DK_ * DV_) / 4)] = run;
      float4 tv = src[(size_t)cc * ((DK_ * DV_) / 4)];
      run.x += tv.x; run.y += tv.y; run.z += tv.z; run.w += tv.w;
    }
  } else {
    int e2 = e - (DK_ * DV_) / 4;
    const float4* src = (const float4*)(lks + (size_t)bh * NC_ * DK_) + e2;
    float4* dst = (float4*)(pks + (size_t)bh * NC_ * DK_) + e2;
    for (int cc = 0; cc < NC_; ++cc) {
      dst[(size_t)cc * (DK_ / 4)] = run;
      float4 tv = src[(size_t)cc * (DK_ / 4)];
      run.x += tv.x; run.y += tv.y; run.z += tv.z; run.w += tv.w;
    }
  }
}

// ---------------------------------------------------------------------------
// Kernel 4: outputs for one chunk (round-1 proven version).
// ---------------------------------------------------------------------------
__global__ __launch_bounds__(256) void out_kernel(const float* __restrict__ qg,
                                                  const float* __restrict__ kg,
                                                  const float* __restrict__ vg,
                                                  const float* __restrict__ qc,
                                                  const float* __restrict__ kc,
                                                  const float* __restrict__ ksum,
                                                  const float* __restrict__ kvsum,
                                                  float* __restrict__ outg) {
  __shared__ float qbT[DK_][C_];
  __shared__ float kbT[DK_][C_];
  __shared__ float vs[C_][DV_];
  int chunk = blockIdx.x;
  int bh = chunk / NC_, ci = chunk - bh * NC_;
  int r0 = ci * C_;
  size_t gbase = ((size_t)bh * N_ + r0) * DK_;
  int t = threadIdx.x;
  {
    int i = t & 63;
    int apart = t >> 6;
    float qsc = qc[bh * N_ + r0 + i];
    float ksc = kc[bh * N_ + r0 + i];
#pragma unroll
    for (int u = 0; u < 4; ++u) {
      int a0 = apart * 16 + u * 4;
      float4 q4 = *(const float4*)(qg + gbase + (size_t)i * DK_ + a0);
      float4 k4 = *(const float4*)(kg + gbase + (size_t)i * DK_ + a0);
      qbT[a0 + 0][i] = q4.x * qsc; qbT[a0 + 1][i] = q4.y * qsc;
      qbT[a0 + 2][i] = q4.z * qsc; qbT[a0 + 3][i] = q4.w * qsc;
      kbT[a0 + 0][i] = k4.x * ksc; kbT[a0 + 1][i] = k4.y * ksc;
      kbT[a0 + 2][i] = k4.z * ksc; kbT[a0 + 3][i] = k4.w * ksc;
    }
#pragma unroll
    for (int p = 0; p < 4; ++p) {
      int f = t + p * 256;
      int row = f >> 4, col = (f & 15) * 4;
      *(float4*)&vs[row][col] = *(const float4*)(vg + gbase + (size_t)f * 4);
    }
  }
  __syncthreads();
  int i0 = (t & 15) * 4, j0 = (t >> 4) * 4;
  float acc[4][4] = {};
  for (int a = 0; a < DK_; ++a) {
    float4 q4 = *(const float4*)&qbT[a][i0];
    float4 k4 = *(const float4*)&kbT[a][j0];
    float qa[4] = {q4.x, q4.y, q4.z, q4.w};
    float kk[4] = {k4.x, k4.y, k4.z, k4.w};
#pragma unroll
    for (int ii = 0; ii < 4; ++ii)
#pragma unroll
      for (int jj = 0; jj < 4; ++jj) acc[ii][jj] += qa[ii] * kk[jj];
  }
  __syncthreads();
  float (*St)[C_] = kbT;
#pragma unroll
  for (int jj = 0; jj < 4; ++jj) {
    int j = j0 + jj;
    float4 w;
    w.x = (j <= i0 + 0) ? acc[0][jj] : 0.f;
    w.y = (j <= i0 + 1) ? acc[1][jj] : 0.f;
    w.z = (j <= i0 + 2) ? acc[2][jj] : 0.f;
    w.w = (j <= i0 + 3) ? acc[3][jj] : 0.f;
    *(float4*)&St[j][i0] = w;
  }
  __syncthreads();
  {
    int bi0 = (t >> 4) * 4, c0 = (t & 15) * 4;
    const float* kvp = kvsum + (size_t)chunk * (DK_ * DV_);
    const float* tp = ksum + (size_t)chunk * DK_;
    float o[4][4] = {};
    float pp[4] = {};
    for (int a = 0; a < DK_; ++a) {
      float4 q4 = *(const float4*)&qbT[a][bi0];
      float4 d4 = *(const float4*)(kvp + (size_t)a * DV_ + c0);
      float tv = tp[a];
      float qa[4] = {q4.x, q4.y, q4.z, q4.w};
      float da[4] = {d4.x, d4.y, d4.z, d4.w};
#pragma unroll
      for (int ii = 0; ii < 4; ++ii) {
        pp[ii] += qa[ii] * tv;
#pragma unroll
        for (int cc = 0; cc < 4; ++cc) o[ii][cc] += qa[ii] * da[cc];
      }
    }
    for (int j = 0; j < C_; ++j) {
      float4 s4 = *(const float4*)&St[j][bi0];
      float4 v4 = *(const float4*)&vs[j][c0];
      float sa[4] = {s4.x, s4.y, s4.z, s4.w};
      float va[4] = {v4.x, v4.y, v4.z, v4.w};
#pragma unroll
      for (int ii = 0; ii < 4; ++ii) {
        pp[ii] += sa[ii];
#pragma unroll
        for (int cc = 0; cc < 4; ++cc) o[ii][cc] += sa[ii] * va[cc];
      }
    }
    float* obp = outg + ((size_t)bh * N_ + r0) * DV_;
#pragma unroll
    for (int ii = 0; ii < 4; ++ii) {
      float P = fmaxf(fabsf(pp[ii]), 1.0f);
      float inv = 1.0f / P;
      *(float4*)(obp + (size_t)(bi0 + ii) * DV_ + c0) =
          make_float4(o[ii][0] * inv, o[ii][1] * inv,
                      o[ii][2] * inv, o[ii][3] * inv);
    }
  }
}

// ---------------------------------------------------------------------------
extern "C" void kernel_launch(void* const* d_in, const int* in_sizes, int n_in,
                              void* d_out, int out_size, void* d_ws, size_t ws_size,
                              hipStream_t stream) {
  const float* q = (const float*)d_in[0];
  const float* k = (const float*)d_in[1];
  const float* v = (const float*)d_in[2];
  const float* om = (const float*)d_in[3];
  float* out = (float*)d_out;

  float* ws = (float*)d_ws;
  float* lksum = ws;                               // NCH_*DK_       = 32768
  float* lkv = lksum + (size_t)NCH_ * DK_;         // NCH_*DK_*DV_   = 2,097,152
  float* pksum = lkv + (size_t)NCH_ * DK_ * DV_;   // NCH_*DK_       = 32768
  float* pkv = pksum + (size_t)NCH_ * DK_;         // NCH_*DK_*DV_   = 2,097,152
  float* qc = pkv + (size_t)NCH_ * DK_ * DV_;      // BH_*N_         = 32768
  float* kc = qc + BH_ * N_;                       // BH_*N_         = 32768

  coef_kernel<<<BH_ * N_ / 8, 256, 0, stream>>>(om, qc, kc);
  chunksum_kernel<<<NCH_, 256, 0, stream>>>(k, v, kc, lksum, lkv);
  constexpr int SCAN4 = BH_ * ((DK_ * DV_) / 4 + DK_ / 4);
  scan_kernel<<<(SCAN4 + 255) / 256, 256, 0, stream>>>(lksum, lkv, pksum, pkv);
  out_kernel<<<NCH_, 256, 0, stream>>>(q, k, v, qc, kc, pksum, pkv, out);
}

// Round 5
// 80.786 us; speedup vs baseline: 2.7664x; 1.0157x over previous
//
#include <hip/hip_runtime.h>
#include <cmath>

constexpr int B_ = 2, H_ = 8, N_ = 2048, DK_ = 64, DV_ = 64;
constexpr int BH_ = B_ * H_;      // 16
constexpr int C_ = 64;            // chunk size
constexpr int NC_ = N_ / C_;      // 32 chunks per (b,h)
constexpr int NCH_ = BH_ * NC_;   // 512 chunks total

// ---------------------------------------------------------------------------
// Kernel 1: per-row coefficients (EXACT round-1 shape — empirically fastest).
// qc[i] = omask[i,0]/sqrt(sum_j omask[i,j]);  kc[i] = 1/omask[i,0]
// One wave per row, 4 rows per 256-thread block, 8192 blocks.
// ---------------------------------------------------------------------------
__global__ __launch_bounds__(256) void coef_kernel(const float* __restrict__ om,
                                                   float* __restrict__ qc,
                                                   float* __restrict__ kc) {
  int row = blockIdx.x * 4 + (threadIdx.x >> 6);
  int lane = threadIdx.x & 63;
  const float* r = om + (size_t)row * N_;
  float s = 0.f;
#pragma unroll
  for (int kk = 0; kk < N_ / 256; ++kk) {
    float4 v4 = *(const float4*)(r + kk * 256 + lane * 4);
    s += (v4.x + v4.y) + (v4.z + v4.w);
  }
#pragma unroll
  for (int off = 32; off > 0; off >>= 1) s += __shfl_xor(s, off, 64);
  if (lane == 0) {
    float o0 = r[0];
    qc[row] = o0 / sqrtf(s);
    kc[row] = 1.0f / o0;
  }
}

// ---------------------------------------------------------------------------
// Kernel 2: per-chunk sums  ksum[dk] = sum_r kbar[r][dk],
//                           kv[dk][dv] = sum_r kbar[r][dk]*v[r][dv]
// ---------------------------------------------------------------------------
__global__ __launch_bounds__(256) void chunksum_kernel(const float* __restrict__ kg,
                                                       const float* __restrict__ vg,
                                                       const float* __restrict__ kc,
                                                       float* __restrict__ ksum,
                                                       float* __restrict__ kvsum) {
  __shared__ float kb[C_][DK_];
  __shared__ float vs[C_][DV_];
  int chunk = blockIdx.x;
  int bh = chunk / NC_, ci = chunk - bh * NC_;
  int r0 = ci * C_;
  size_t gbase = ((size_t)bh * N_ + r0) * DK_;
  int t = threadIdx.x;
#pragma unroll
  for (int p = 0; p < 4; ++p) {
    int f = t + p * 256;
    int row = f >> 4, col = (f & 15) * 4;
    float sc = kc[bh * N_ + r0 + row];
    float4 k4 = *(const float4*)(kg + gbase + (size_t)f * 4);
    k4.x *= sc; k4.y *= sc; k4.z *= sc; k4.w *= sc;
    *(float4*)&kb[row][col] = k4;
    *(float4*)&vs[row][col] = *(const float4*)(vg + gbase + (size_t)f * 4);
  }
  __syncthreads();
  int dk0 = (t & 15) * 4, dv0 = (t >> 4) * 4;
  float acc[4][4] = {};
  float ks[4] = {};
  for (int r = 0; r < C_; ++r) {
    float4 k4 = *(const float4*)&kb[r][dk0];
    float4 v4 = *(const float4*)&vs[r][dv0];
    float ka[4] = {k4.x, k4.y, k4.z, k4.w};
    float va[4] = {v4.x, v4.y, v4.z, v4.w};
#pragma unroll
    for (int i = 0; i < 4; ++i) {
      ks[i] += ka[i];
#pragma unroll
      for (int j = 0; j < 4; ++j) acc[i][j] += ka[i] * va[j];
    }
  }
  float* kvc = kvsum + (size_t)chunk * (DK_ * DV_);
#pragma unroll
  for (int i = 0; i < 4; ++i)
    *(float4*)(kvc + (size_t)(dk0 + i) * DV_ + dv0) =
        make_float4(acc[i][0], acc[i][1], acc[i][2], acc[i][3]);
  if (t < 16) {
#pragma unroll
    for (int i = 0; i < 4; ++i) ksum[(size_t)chunk * DK_ + dk0 + i] = ks[i];
  }
}

// ---------------------------------------------------------------------------
// Kernel 3: exclusive prefix over chunks (per bh), float4 per thread,
// 8-deep load pipelining so the 32-step chain costs ~4 load latencies.
// ---------------------------------------------------------------------------
__global__ __launch_bounds__(256) void scan_kernel(const float* __restrict__ lks,
                                                   const float* __restrict__ lkv,
                                                   float* __restrict__ pks,
                                                   float* __restrict__ pkv) {
  constexpr int PER4 = (DK_ * DV_) / 4 + DK_ / 4;   // 1024 + 16 = 1040
  int idx = blockIdx.x * 256 + threadIdx.x;
  if (idx >= BH_ * PER4) return;
  int bh = idx / PER4, e = idx - bh * PER4;
  const float4* src;
  float4* dst;
  size_t stride;
  if (e < (DK_ * DV_) / 4) {
    src = (const float4*)(lkv + (size_t)bh * NC_ * (DK_ * DV_)) + e;
    dst = (float4*)(pkv + (size_t)bh * NC_ * (DK_ * DV_)) + e;
    stride = (DK_ * DV_) / 4;
  } else {
    int e2 = e - (DK_ * DV_) / 4;
    src = (const float4*)(lks + (size_t)bh * NC_ * DK_) + e2;
    dst = (float4*)(pks + (size_t)bh * NC_ * DK_) + e2;
    stride = DK_ / 4;
  }
  float4 run = make_float4(0.f, 0.f, 0.f, 0.f);
  float4 buf[8];
  for (int b = 0; b < NC_ / 8; ++b) {
#pragma unroll
    for (int i = 0; i < 8; ++i) buf[i] = src[(size_t)(b * 8 + i) * stride];
#pragma unroll
    for (int i = 0; i < 8; ++i) {
      dst[(size_t)(b * 8 + i) * stride] = run;
      run.x += buf[i].x; run.y += buf[i].y;
      run.z += buf[i].z; run.w += buf[i].w;
    }
  }
}

// ---------------------------------------------------------------------------
// Kernel 4: outputs for one chunk (round-1 proven version).
// ---------------------------------------------------------------------------
__global__ __launch_bounds__(256) void out_kernel(const float* __restrict__ qg,
                                                  const float* __restrict__ kg,
                                                  const float* __restrict__ vg,
                                                  const float* __restrict__ qc,
                                                  const float* __restrict__ kc,
                                                  const float* __restrict__ ksum,
                                                  const float* __restrict__ kvsum,
                                                  float* __restrict__ outg) {
  __shared__ float qbT[DK_][C_];
  __shared__ float kbT[DK_][C_];
  __shared__ float vs[C_][DV_];
  int chunk = blockIdx.x;
  int bh = chunk / NC_, ci = chunk - bh * NC_;
  int r0 = ci * C_;
  size_t gbase = ((size_t)bh * N_ + r0) * DK_;
  int t = threadIdx.x;
  {
    int i = t & 63;
    int apart = t >> 6;
    float qsc = qc[bh * N_ + r0 + i];
    float ksc = kc[bh * N_ + r0 + i];
#pragma unroll
    for (int u = 0; u < 4; ++u) {
      int a0 = apart * 16 + u * 4;
      float4 q4 = *(const float4*)(qg + gbase + (size_t)i * DK_ + a0);
      float4 k4 = *(const float4*)(kg + gbase + (size_t)i * DK_ + a0);
      qbT[a0 + 0][i] = q4.x * qsc; qbT[a0 + 1][i] = q4.y * qsc;
      qbT[a0 + 2][i] = q4.z * qsc; qbT[a0 + 3][i] = q4.w * qsc;
      kbT[a0 + 0][i] = k4.x * ksc; kbT[a0 + 1][i] = k4.y * ksc;
      kbT[a0 + 2][i] = k4.z * ksc; kbT[a0 + 3][i] = k4.w * ksc;
    }
#pragma unroll
    for (int p = 0; p < 4; ++p) {
      int f = t + p * 256;
      int row = f >> 4, col = (f & 15) * 4;
      *(float4*)&vs[row][col] = *(const float4*)(vg + gbase + (size_t)f * 4);
    }
  }
  __syncthreads();
  int i0 = (t & 15) * 4, j0 = (t >> 4) * 4;
  float acc[4][4] = {};
  for (int a = 0; a < DK_; ++a) {
    float4 q4 = *(const float4*)&qbT[a][i0];
    float4 k4 = *(const float4*)&kbT[a][j0];
    float qa[4] = {q4.x, q4.y, q4.z, q4.w};
    float kk[4] = {k4.x, k4.y, k4.z, k4.w};
#pragma unroll
    for (int ii = 0; ii < 4; ++ii)
#pragma unroll
      for (int jj = 0; jj < 4; ++jj) acc[ii][jj] += qa[ii] * kk[jj];
  }
  __syncthreads();
  float (*St)[C_] = kbT;
#pragma unroll
  for (int jj = 0; jj < 4; ++jj) {
    int j = j0 + jj;
    float4 w;
    w.x = (j <= i0 + 0) ? acc[0][jj] : 0.f;
    w.y = (j <= i0 + 1) ? acc[1][jj] : 0.f;
    w.z = (j <= i0 + 2) ? acc[2][jj] : 0.f;
    w.w = (j <= i0 + 3) ? acc[3][jj] : 0.f;
    *(float4*)&St[j][i0] = w;
  }
  __syncthreads();
  {
    int bi0 = (t >> 4) * 4, c0 = (t & 15) * 4;
    const float* kvp = kvsum + (size_t)chunk * (DK_ * DV_);
    const float* tp = ksum + (size_t)chunk * DK_;
    float o[4][4] = {};
    float pp[4] = {};
    for (int a = 0; a < DK_; ++a) {
      float4 q4 = *(const float4*)&qbT[a][bi0];
      float4 d4 = *(const float4*)(kvp + (size_t)a * DV_ + c0);
      float tv = tp[a];
      float qa[4] = {q4.x, q4.y, q4.z, q4.w};
      float da[4] = {d4.x, d4.y, d4.z, d4.w};
#pragma unroll
      for (int ii = 0; ii < 4; ++ii) {
        pp[ii] += qa[ii] * tv;
#pragma unroll
        for (int cc = 0; cc < 4; ++cc) o[ii][cc] += qa[ii] * da[cc];
      }
    }
    for (int j = 0; j < C_; ++j) {
      float4 s4 = *(const float4*)&St[j][bi0];
      float4 v4 = *(const float4*)&vs[j][c0];
      float sa[4] = {s4.x, s4.y, s4.z, s4.w};
      float va[4] = {v4.x, v4.y, v4.z, v4.w};
#pragma unroll
      for (int ii = 0; ii < 4; ++ii) {
        pp[ii] += sa[ii];
#pragma unroll
        for (int cc = 0; cc < 4; ++cc) o[ii][cc] += sa[ii] * va[cc];
      }
    }
    float* obp = outg + ((size_t)bh * N_ + r0) * DV_;
#pragma unroll
    for (int ii = 0; ii < 4; ++ii) {
      float P = fmaxf(fabsf(pp[ii]), 1.0f);
      float inv = 1.0f / P;
      *(float4*)(obp + (size_t)(bi0 + ii) * DV_ + c0) =
          make_float4(o[ii][0] * inv, o[ii][1] * inv,
                      o[ii][2] * inv, o[ii][3] * inv);
    }
  }
}

// ---------------------------------------------------------------------------
extern "C" void kernel_launch(void* const* d_in, const int* in_sizes, int n_in,
                              void* d_out, int out_size, void* d_ws, size_t ws_size,
                              hipStream_t stream) {
  const float* q = (const float*)d_in[0];
  const float* k = (const float*)d_in[1];
  const float* v = (const float*)d_in[2];
  const float* om = (const float*)d_in[3];
  float* out = (float*)d_out;

  float* ws = (float*)d_ws;
  float* lksum = ws;                               // NCH_*DK_       = 32768
  float* lkv = lksum + (size_t)NCH_ * DK_;         // NCH_*DK_*DV_   = 2,097,152
  float* pksum = lkv + (size_t)NCH_ * DK_ * DV_;   // NCH_*DK_       = 32768
  float* pkv = pksum + (size_t)NCH_ * DK_;         // NCH_*DK_*DV_   = 2,097,152
  float* qc = pkv + (size_t)NCH_ * DK_ * DV_;      // BH_*N_         = 32768
  float* kc = qc + BH_ * N_;                       // BH_*N_         = 32768

  coef_kernel<<<BH_ * N_ / 4, 256, 0, stream>>>(om, qc, kc);
  chunksum_kernel<<<NCH_, 256, 0, stream>>>(k, v, kc, lksum, lkv);
  constexpr int SCAN4 = BH_ * ((DK_ * DV_) / 4 + DK_ / 4);
  scan_kernel<<<(SCAN4 + 255) / 256, 256, 0, stream>>>(lksum, lkv, pksum, pkv);
  out_kernel<<<NCH_, 256, 0, stream>>>(q, k, v, qc, kc, pksum, pkv, out);
}

// Round 7
// 67.809 us; speedup vs baseline: 3.2958x; 1.1914x over previous
//
#include <hip/hip_runtime.h>
#include <cmath>

constexpr int B_ = 2, H_ = 8, N_ = 2048, DK_ = 64, DV_ = 64;
constexpr int BH_ = B_ * H_;      // 16
constexpr int C_ = 64;            // chunk size
constexpr int NC_ = N_ / C_;      // 32 chunks per (b,h)
constexpr int NCH_ = BH_ * NC_;   // 512 chunks total

using f32x16 = __attribute__((ext_vector_type(16))) float;
using bf16x8 = __attribute__((ext_vector_type(8))) __bf16;

// float -> bf16 bits, round-to-nearest-even
__device__ inline unsigned short bfr(float x) {
  unsigned u = __float_as_uint(x);
  return (unsigned short)((u + 0x7FFFu + ((u >> 16) & 1u)) >> 16);
}
__device__ inline unsigned pk2(float lo, float hi) {
  return (unsigned)bfr(lo) | ((unsigned)bfr(hi) << 16);
}
// swizzled ushort index into a [64][64] bf16 tile (row stride 128B),
// byte ^= (row&7)<<4 — spreads fixed-column fragment reads across banks.
__device__ inline int swi(int row, int a) {
  return (row * 128 + (((a * 2) ^ ((row & 7) << 4)))) >> 1;
}

// ---------------------------------------------------------------------------
// Kernel 1: per-row coefficients (round-1 proven shape).
// ---------------------------------------------------------------------------
__global__ __launch_bounds__(256) void coef_kernel(const float* __restrict__ om,
                                                   float* __restrict__ qc,
                                                   float* __restrict__ kc) {
  int row = blockIdx.x * 4 + (threadIdx.x >> 6);
  int lane = threadIdx.x & 63;
  const float* r = om + (size_t)row * N_;
  float s = 0.f;
#pragma unroll
  for (int kk = 0; kk < N_ / 256; ++kk) {
    float4 v4 = *(const float4*)(r + kk * 256 + lane * 4);
    s += (v4.x + v4.y) + (v4.z + v4.w);
  }
#pragma unroll
  for (int off = 32; off > 0; off >>= 1) s += __shfl_xor(s, off, 64);
  if (lane == 0) {
    float o0 = r[0];
    qc[row] = o0 / sqrtf(s);
    kc[row] = 1.0f / o0;
  }
}

// ---------------------------------------------------------------------------
// Kernel 2: per-chunk sums (round-1 proven version).
// ---------------------------------------------------------------------------
__global__ __launch_bounds__(256) void chunksum_kernel(const float* __restrict__ kg,
                                                       const float* __restrict__ vg,
                                                       const float* __restrict__ kc,
                                                       float* __restrict__ ksum,
                                                       float* __restrict__ kvsum) {
  __shared__ float kb[C_][DK_];
  __shared__ float vs[C_][DV_];
  int chunk = blockIdx.x;
  int bh = chunk / NC_, ci = chunk - bh * NC_;
  int r0 = ci * C_;
  size_t gbase = ((size_t)bh * N_ + r0) * DK_;
  int t = threadIdx.x;
#pragma unroll
  for (int p = 0; p < 4; ++p) {
    int f = t + p * 256;
    int row = f >> 4, col = (f & 15) * 4;
    float sc = kc[bh * N_ + r0 + row];
    float4 k4 = *(const float4*)(kg + gbase + (size_t)f * 4);
    k4.x *= sc; k4.y *= sc; k4.z *= sc; k4.w *= sc;
    *(float4*)&kb[row][col] = k4;
    *(float4*)&vs[row][col] = *(const float4*)(vg + gbase + (size_t)f * 4);
  }
  __syncthreads();
  int dk0 = (t & 15) * 4, dv0 = (t >> 4) * 4;
  float acc[4][4] = {};
  float ks[4] = {};
  for (int r = 0; r < C_; ++r) {
    float4 k4 = *(const float4*)&kb[r][dk0];
    float4 v4 = *(const float4*)&vs[r][dv0];
    float ka[4] = {k4.x, k4.y, k4.z, k4.w};
    float va[4] = {v4.x, v4.y, v4.z, v4.w};
#pragma unroll
    for (int i = 0; i < 4; ++i) {
      ks[i] += ka[i];
#pragma unroll
      for (int j = 0; j < 4; ++j) acc[i][j] += ka[i] * va[j];
    }
  }
  float* kvc = kvsum + (size_t)chunk * (DK_ * DV_);
#pragma unroll
  for (int i = 0; i < 4; ++i)
    *(float4*)(kvc + (size_t)(dk0 + i) * DV_ + dv0) =
        make_float4(acc[i][0], acc[i][1], acc[i][2], acc[i][3]);
  if (t < 16) {
#pragma unroll
    for (int i = 0; i < 4; ++i) ksum[(size_t)chunk * DK_ + dk0 + i] = ks[i];
  }
}

// ---------------------------------------------------------------------------
// Kernel 3: exclusive prefix over chunks (round-1 in-place version).
// ---------------------------------------------------------------------------
__global__ __launch_bounds__(256) void scan_kernel(float* __restrict__ ksum,
                                                   float* __restrict__ kvsum) {
  constexpr int PER = DK_ * DV_ + DK_;   // 4160 elements per bh
  int idx = blockIdx.x * 256 + threadIdx.x;
  if (idx >= BH_ * PER) return;
  int bh = idx / PER, e = idx - bh * PER;
  float run = 0.f;
  if (e < DK_ * DV_) {
    float* p = kvsum + (size_t)bh * NC_ * (DK_ * DV_) + e;
    for (int ci = 0; ci < NC_; ++ci) {
      float tv = p[(size_t)ci * (DK_ * DV_)];
      p[(size_t)ci * (DK_ * DV_)] = run;
      run += tv;
    }
  } else {
    float* p = ksum + (size_t)bh * NC_ * DK_ + (e - DK_ * DV_);
    for (int ci = 0; ci < NC_; ++ci) {
      float tv = p[(size_t)ci * DK_];
      p[(size_t)ci * DK_] = run;
      run += tv;
    }
  }
}

// ---------------------------------------------------------------------------
// Kernel 4 (MFMA numerator + f32 P):
//   S = Q̄·K̄ᵀ (causal, bf16 MFMA), O_num = S·V + Q̄·D_pre (bf16 MFMA),
//   P[i] = q̄_i·(T_pre + cumsum_chunk(k̄)[i])  — FULL f32 (no bf16 anywhere),
//   out = O_num / max(|P|,1).
// P in f32 is essential: P is a cancelling sum; bf16-rounded inputs gave
// ~28% output error in round 6. The numerator only needs relative accuracy.
// ---------------------------------------------------------------------------
__global__ __launch_bounds__(256) void out_mfma_kernel(
    const float* __restrict__ qg, const float* __restrict__ kg,
    const float* __restrict__ vg, const float* __restrict__ qc,
    const float* __restrict__ kc, const float* __restrict__ ksum,
    const float* __restrict__ kvsum, float* __restrict__ outg) {
  __shared__ unsigned short qb[64 * 64];   // q̄[i][a]  bf16, swizzled
  __shared__ unsigned short kb[64 * 64];   // k̄[j][a]  bf16, swizzled
  __shared__ unsigned short sS[64 * 64];   // S[i][j]  bf16, swizzled
  __shared__ unsigned short vT[64 * 64];   // V^T[c][j] bf16, swizzled
  __shared__ unsigned short dT[64 * 64];   // D^T[c][a] bf16, swizzled
  __shared__ float Tc[2][64][68];          // f32 in-chunk cumsum of k̄ (+4 pad)
  __shared__ float Tl[64];                 // f32 T_pre
  __shared__ float Pf[64];                 // 1/P

  const int chunk = blockIdx.x;
  const int bh = chunk >> 5, ci = chunk & 31;
  const int r0 = ci * C_;
  const int rowb = bh * N_ + r0;
  const size_t gbase = (size_t)rowb * DK_;
  const int t = threadIdx.x;
  const int i = t >> 2, a0 = (t & 3) * 16;

  // ---- staging ----
  float xq[16];
  {
    float qcv = qc[rowb + i];
    float kcv = kc[rowb + i];
    float xk[16], xv[16], xd[16];
    {
      const float* qp = qg + gbase + (size_t)i * 64 + a0;
      const float* kp = kg + gbase + (size_t)i * 64 + a0;
      const float* vp = vg + gbase + (size_t)i * 64 + a0;
      const float* dp = kvsum + (size_t)chunk * (DK_ * DV_) + (size_t)i * 64 + a0;
#pragma unroll
      for (int u = 0; u < 4; ++u) {
        *(float4*)&xq[u * 4] = *(const float4*)(qp + u * 4);
        *(float4*)&xk[u * 4] = *(const float4*)(kp + u * 4);
        *(float4*)&xv[u * 4] = *(const float4*)(vp + u * 4);
        *(float4*)&xd[u * 4] = *(const float4*)(dp + u * 4);
      }
    }
#pragma unroll
    for (int u = 0; u < 16; ++u) { xq[u] *= qcv; xk[u] *= kcv; }
    // f32 k̄ seeds the in-chunk cumsum
#pragma unroll
    for (int u4 = 0; u4 < 4; ++u4)
      *(float4*)&Tc[0][i][a0 + u4 * 4] = *(const float4*)&xk[u4 * 4];
    unsigned* qbu = (unsigned*)qb;
    unsigned* kbu = (unsigned*)kb;
#pragma unroll
    for (int u = 0; u < 8; ++u) {
      int a = a0 + 2 * u;
      int bi = (i * 128 + (((a * 2) ^ ((i & 7) << 4)))) >> 2;
      qbu[bi] = pk2(xq[2 * u], xq[2 * u + 1]);
      kbu[bi] = pk2(xk[2 * u], xk[2 * u + 1]);
    }
#pragma unroll
    for (int u = 0; u < 16; ++u) {
      int c = a0 + u;
      vT[swi(c, i)] = bfr(xv[u]);           // V^T[c][j=i]
      dT[swi(c, i)] = bfr(xd[u]);           // D^T[c][a=i]
    }
    if (t < 64) Tl[t] = ksum[(size_t)chunk * DK_ + t];
  }
  __syncthreads();

  // ---- f32 in-chunk inclusive cumsum of k̄ over rows (Hillis-Steele) ----
  {
    int p = 0;
#pragma unroll
    for (int step = 1; step < 64; step <<= 1) {
      float4 cur[4], prv[4];
#pragma unroll
      for (int u4 = 0; u4 < 4; ++u4) {
        cur[u4] = *(const float4*)&Tc[p][i][a0 + u4 * 4];
        if (i >= step)
          prv[u4] = *(const float4*)&Tc[p][i - step][a0 + u4 * 4];
        else
          prv[u4] = make_float4(0.f, 0.f, 0.f, 0.f);
      }
#pragma unroll
      for (int u4 = 0; u4 < 4; ++u4) {
        float4 w = make_float4(cur[u4].x + prv[u4].x, cur[u4].y + prv[u4].y,
                               cur[u4].z + prv[u4].z, cur[u4].w + prv[u4].w);
        *(float4*)&Tc[p ^ 1][i][a0 + u4 * 4] = w;
      }
      __syncthreads();
      p ^= 1;
    }
    // result in Tc[0]
  }

  // ---- P[i] = q̄_i·(T_pre + Tc[i])  (all f32) ----
  {
    float part = 0.f;
#pragma unroll
    for (int u = 0; u < 16; ++u)
      part += xq[u] * (Tl[a0 + u] + Tc[0][i][a0 + u]);
    part += __shfl_xor(part, 1, 64);
    part += __shfl_xor(part, 2, 64);
    if ((t & 3) == 0) Pf[i] = 1.0f / fmaxf(fabsf(part), 1.0f);
  }

  const int lane = t & 63, w = t >> 6;
  const int wr = w >> 1, wc = w & 1;
  const int half = lane >> 5, col = lane & 31;
  const int arow = 32 * wr + col;           // A-fragment row for this lane
  const int bcol = 32 * wc + col;           // B-fragment col for this lane

  // ---- M1: S = Q̄ K̄ᵀ ----
  f32x16 accS;
#pragma unroll
  for (int r = 0; r < 16; ++r) accS[r] = 0.f;
#pragma unroll
  for (int kk = 0; kk < 4; ++kk) {
    int aa = kk * 16 + half * 8;
    bf16x8 af = *(const bf16x8*)&qb[swi(arow, aa)];
    bf16x8 bf = *(const bf16x8*)&kb[swi(bcol, aa)];
    accS = __builtin_amdgcn_mfma_f32_32x32x16_bf16(af, bf, accS, 0, 0, 0);
  }
  // causal mask, write S (bf16)
#pragma unroll
  for (int r = 0; r < 16; ++r) {
    int iloc = (r & 3) + 8 * (r >> 2) + 4 * half;
    int ii = 32 * wr + iloc;
    int jj = 32 * wc + col;
    float m = (jj <= ii) ? accS[r] : 0.f;
    sS[swi(ii, jj)] = bfr(m);
  }
  __syncthreads();   // sS + Pf visible

  // ---- M2+M3: O = S·V + Q̄·D ----
  f32x16 acc;
#pragma unroll
  for (int r = 0; r < 16; ++r) acc[r] = 0.f;
#pragma unroll
  for (int kk = 0; kk < 4; ++kk) {
    int j0 = kk * 16 + half * 8;
    bf16x8 af = *(const bf16x8*)&sS[swi(arow, j0)];
    bf16x8 bf = *(const bf16x8*)&vT[swi(bcol, j0)];
    acc = __builtin_amdgcn_mfma_f32_32x32x16_bf16(af, bf, acc, 0, 0, 0);
  }
#pragma unroll
  for (int kk = 0; kk < 4; ++kk) {
    int aa = kk * 16 + half * 8;
    bf16x8 af = *(const bf16x8*)&qb[swi(arow, aa)];
    bf16x8 bf = *(const bf16x8*)&dT[swi(bcol, aa)];
    acc = __builtin_amdgcn_mfma_f32_32x32x16_bf16(af, bf, acc, 0, 0, 0);
  }

  // ---- epilogue ----
  float* ob = outg + (size_t)rowb * DV_;
#pragma unroll
  for (int r = 0; r < 16; ++r) {
    int iloc = (r & 3) + 8 * (r >> 2) + 4 * half;
    int ii = 32 * wr + iloc;
    int cc = 32 * wc + col;
    ob[(size_t)ii * DV_ + cc] = acc[r] * Pf[ii];
  }
}

// ---------------------------------------------------------------------------
extern "C" void kernel_launch(void* const* d_in, const int* in_sizes, int n_in,
                              void* d_out, int out_size, void* d_ws, size_t ws_size,
                              hipStream_t stream) {
  const float* q = (const float*)d_in[0];
  const float* k = (const float*)d_in[1];
  const float* v = (const float*)d_in[2];
  const float* om = (const float*)d_in[3];
  float* out = (float*)d_out;

  float* ws = (float*)d_ws;
  float* qc = ws;                          // BH_*N_      = 32768
  float* kc = qc + BH_ * N_;               // BH_*N_      = 32768
  float* ksum = kc + BH_ * N_;             // NCH_*DK_    = 32768
  float* kv = ksum + (size_t)NCH_ * DK_;   // NCH_*DK_*DV_ = 2,097,152

  coef_kernel<<<BH_ * N_ / 4, 256, 0, stream>>>(om, qc, kc);
  chunksum_kernel<<<NCH_, 256, 0, stream>>>(k, v, kc, ksum, kv);
  constexpr int SCAN_TOTAL = BH_ * (DK_ * DV_ + DK_);
  scan_kernel<<<(SCAN_TOTAL + 255) / 256, 256, 0, stream>>>(ksum, kv);
  out_mfma_kernel<<<NCH_, 256, 0, stream>>>(q, k, v, qc, kc, ksum, kv, out);
}